// Round 19
// baseline (203.509 us; speedup 1.0000x reference)
//
#include <hip/hip_runtime.h>
#include <hip/hip_fp16.h>
#include <math.h>

#define N_NODES 100000
#define N_EDGES 1250000
#define D 64
#define EPS 1e-8f

#define ZERO_BLOCKS 391     // ceil(100000/256)
#define GEMM_BLOCKS 1024
#define NODE_BLOCKS 391     // ceil(100000/256)
#define COSR_BLOCKS 9766    // ceil((N_EDGES/4)*8 / 256)
#define EDGE_BLOCKS 4883    // ceil(1250000/256)

// ---------------------------------------------------------------------------
// Fused: cnt64 zeroing (blocks 0..390) + hn = normalize(tanh(xW^T+b)) -> fp16
// ---------------------------------------------------------------------------
__global__ __launch_bounds__(256) void k_gemm_zero(
    const float* __restrict__ x, const float* __restrict__ W,
    const float* __restrict__ b, __half* __restrict__ hn,
    unsigned long long* __restrict__ cnt64)
{
    if (blockIdx.x < ZERO_BLOCKS) {
        int i = blockIdx.x * 256 + threadIdx.x;
        if (i < N_NODES) cnt64[i] = 0ULL;
        return;
    }
    __shared__ float xrow[4][72];
    const int lane = threadIdx.x & 63;
    const int wid  = threadIdx.x >> 6;

    float Wreg[64];
    const float4* Wv = (const float4*)(W + lane * D);
    #pragma unroll
    for (int q = 0; q < 16; ++q) {
        float4 w4 = Wv[q];
        Wreg[4*q+0] = w4.x; Wreg[4*q+1] = w4.y;
        Wreg[4*q+2] = w4.z; Wreg[4*q+3] = w4.w;
    }
    const float bj = b[lane];
    float* xl = xrow[wid];

    const int wave   = (blockIdx.x - ZERO_BLOCKS) * 4 + wid;
    const int nwaves = GEMM_BLOCKS * 4;

    for (int row = wave; row < N_NODES; row += nwaves) {
        float xv = x[(size_t)row * D + lane];
        xl[lane] = xv;
        float acc = bj;
        #pragma unroll
        for (int q = 0; q < 16; ++q) {
            float4 xk4 = *(const float4*)(xl + 4*q);
            acc = fmaf(xk4.x, Wreg[4*q+0], acc);
            acc = fmaf(xk4.y, Wreg[4*q+1], acc);
            acc = fmaf(xk4.z, Wreg[4*q+2], acc);
            acc = fmaf(xk4.w, Wreg[4*q+3], acc);
        }
        float h = tanhf(acc);
        float s = h * h;
        #pragma unroll
        for (int m = 32; m >= 1; m >>= 1) s += __shfl_xor(s, m, 64);
        float nrm = fmaxf(sqrtf(s), EPS);
        hn[(size_t)row * D + lane] = __float2half_rn(h / nrm);
    }
}

// ---------------------------------------------------------------------------
// Fused cosine + NONZERO rank + deg-sum via ONE packed 64-bit atomic:
//   cnt64[d] += (1<<40) | (ull)(w * 2^32)
// rank stored as UCHAR. 8 lanes/edge, 4 edges/group, 8 gathers in flight.
// ---------------------------------------------------------------------------
__device__ __forceinline__ float dot8h(float4 a, float4 c)
{
    const __half2* ah = (const __half2*)&a;
    const __half2* ch = (const __half2*)&c;
    float p = 0.0f;
    #pragma unroll
    for (int q = 0; q < 4; ++q) {
        float2 af = __half22float2(ah[q]);
        float2 cf = __half22float2(ch[q]);
        p = fmaf(af.x, cf.x, p);
        p = fmaf(af.y, cf.y, p);
    }
    return p;
}

__global__ __launch_bounds__(256) void k_cos_rank(
    const int* __restrict__ ei, const __half* __restrict__ hn,
    unsigned long long* __restrict__ cnt64, unsigned char* __restrict__ rank,
    float* __restrict__ wout)
{
    int t = blockIdx.x * 256 + threadIdx.x;
    int g = t >> 3, sub = t & 7;
    if (g >= N_EDGES / 4) return;
    int e0 = g * 4;
    int4 ss = *(const int4*)(ei + e0);
    int4 dd = *(const int4*)(ei + N_EDGES + e0);

    float4 a0 = ((const float4*)(hn + (size_t)ss.x * D))[sub];
    float4 c0 = ((const float4*)(hn + (size_t)dd.x * D))[sub];
    float4 a1 = ((const float4*)(hn + (size_t)ss.y * D))[sub];
    float4 c1 = ((const float4*)(hn + (size_t)dd.y * D))[sub];
    float4 a2 = ((const float4*)(hn + (size_t)ss.z * D))[sub];
    float4 c2 = ((const float4*)(hn + (size_t)dd.z * D))[sub];
    float4 a3 = ((const float4*)(hn + (size_t)ss.w * D))[sub];
    float4 c3 = ((const float4*)(hn + (size_t)dd.w * D))[sub];

    float p0 = dot8h(a0, c0);
    float p1 = dot8h(a1, c1);
    float p2 = dot8h(a2, c2);
    float p3 = dot8h(a3, c3);
    // butterfly over the 8-lane group: ALL lanes end with the full sums
    p0 += __shfl_xor(p0, 1, 64);  p1 += __shfl_xor(p1, 1, 64);
    p2 += __shfl_xor(p2, 1, 64);  p3 += __shfl_xor(p3, 1, 64);
    p0 += __shfl_xor(p0, 2, 64);  p1 += __shfl_xor(p1, 2, 64);
    p2 += __shfl_xor(p2, 2, 64);  p3 += __shfl_xor(p3, 2, 64);
    p0 += __shfl_xor(p0, 4, 64);  p1 += __shfl_xor(p1, 4, 64);
    p2 += __shfl_xor(p2, 4, 64);  p3 += __shfl_xor(p3, 4, 64);

    float w0 = fmaxf(p0, 0.0f);
    float w1 = fmaxf(p1, 0.0f);
    float w2 = fmaxf(p2, 0.0f);
    float w3 = fmaxf(p3, 0.0f);

    if (sub == 0) {
        *(float4*)(wout + e0) = make_float4(w0, w1, w2, w3);
    }
    if (sub < 4) {
        float w = (sub == 0) ? w0 : (sub == 1) ? w1 : (sub == 2) ? w2 : w3;
        int   d = (sub == 0) ? dd.x : (sub == 1) ? dd.y : (sub == 2) ? dd.z : dd.w;
        if (w > 0.0f) {
            unsigned long long pack =
                (1ULL << 40) | (unsigned long long)(w * 4294967296.0f);
            unsigned long long old = atomicAdd(cnt64 + d, pack);
            rank[e0 + sub] = (unsigned char)(old >> 40);
        }
    }
}

// ---------------------------------------------------------------------------
// Scan over EVEN-PADDED counts (rows 8B-aligned for uint2 spmv loads) +
// fused per-node constants from cnt64 low bits:
//   A = (1-alpha)*dis^2 ,  B = alpha*dis*relu(mask)
// ---------------------------------------------------------------------------
__device__ __forceinline__ int wave_iscan(int v, int lane)
{
    int incl = v;
    #pragma unroll
    for (int m = 1; m < 64; m <<= 1) {
        int o = __shfl_up(incl, m, 64);
        if (lane >= m) incl += o;
    }
    return incl;
}

__global__ __launch_bounds__(256) void k_scan1(
    const unsigned long long* __restrict__ cnt64, int* __restrict__ rowptr,
    int* __restrict__ bsum, const float* __restrict__ mask,
    const float* __restrict__ alpha_p, float* __restrict__ dis,
    float* __restrict__ y, float* __restrict__ Ac, float* __restrict__ Bc)
{
    __shared__ int wsum[4];
    int t = threadIdx.x, b = blockIdx.x;
    int i = b * 256 + t;
    int lane = t & 63, wid = t >> 6;
    unsigned long long pv = (i < N_NODES) ? cnt64[i] : 0ULL;
    int c = (int)(pv >> 40);
    int v = (c + 1) & ~1;              // even-padded row length
    if (i < N_NODES) {
        float degsum = (float)(pv & 0xFFFFFFFFFFULL) * 2.3283064365386963e-10f; // *2^-32
        float di = rsqrtf(fmaxf(degsum + 1.0f, EPS));   // +1 self-loop
        float al = alpha_p[0];
        float m0 = fmaxf(mask[i], 0.0f);
        dis[i] = di;
        y[i]   = di * m0;
        Ac[i]  = (1.0f - al) * di * di;
        Bc[i]  = al * di * m0;
    }
    int incl = wave_iscan(v, lane);
    if (lane == 63) wsum[wid] = incl;
    __syncthreads();
    int off = 0;
    #pragma unroll
    for (int k = 0; k < 4; ++k) if (k < wid) off += wsum[k];
    if (i < N_NODES) rowptr[i] = off + incl - v;
    if (t == 255) bsum[b] = off + incl;
}

__global__ __launch_bounds__(512) void k_scan2(
    const int* __restrict__ bsum, int* __restrict__ boff, int nblk,
    int* __restrict__ rowptr)
{
    __shared__ int wsum[8];
    int t = threadIdx.x;
    int lane = t & 63, wid = t >> 6;
    int v = (t < nblk) ? bsum[t] : 0;
    int incl = wave_iscan(v, lane);
    if (lane == 63) wsum[wid] = incl;
    __syncthreads();
    int off = 0;
    #pragma unroll
    for (int k = 0; k < 8; ++k) if (k < wid) off += wsum[k];
    if (t < nblk) boff[t] = off + incl - v;
    if (t == nblk - 1) rowptr[N_NODES] = off + incl;   // total padded slots
}

// ---------------------------------------------------------------------------
// CSR placement (edge blocks) + pad-slot zeroing (node blocks, fused).
// pairs[pos] = (src<<15) | w_q15 ; odd rows get one 0-entry pad (exact: it
// contributes 0*y[0] to every sum).
// ---------------------------------------------------------------------------
__global__ __launch_bounds__(256) void k_place(
    const int* __restrict__ ei, const unsigned char* __restrict__ rank_pos,
    const int* __restrict__ rowptr, const int* __restrict__ boff,
    const float* __restrict__ wsrc, const unsigned long long* __restrict__ cnt64,
    unsigned int* __restrict__ pairs)
{
    if (blockIdx.x >= EDGE_BLOCKS) {
        int i = (blockIdx.x - EDGE_BLOCKS) * 256 + threadIdx.x;
        if (i < N_NODES) {
            int c = (int)(cnt64[i] >> 40);
            if (c & 1)
                pairs[rowptr[i] + boff[i >> 8] + c] = 0u;   // pad slot
        }
        return;
    }
    int e = blockIdx.x * 256 + threadIdx.x;
    if (e >= N_EDGES) return;
    float w = wsrc[e];
    if (!(w > 0.0f)) return;
    int s = ei[e];
    int d = ei[N_EDGES + e];
    int pos = rowptr[d] + boff[d >> 8] + (int)rank_pos[e];
    unsigned int wq = (unsigned int)(w * 32767.0f + 0.5f);
    if (wq > 32767u) wq = 32767u;
    pairs[pos] = ((unsigned int)s << 15) | wq;
}

// ---------------------------------------------------------------------------
// FAST APPNP step: y'_i = A_i*(sum/32767 + y_i) + B_i.
// 4 lanes/node, each lane one aligned uint2 (2 slots) per iteration ->
// 8 contiguous slots per iteration with half the load instructions.
// ---------------------------------------------------------------------------
__global__ __launch_bounds__(256) void k_spmv_fast(
    const int* __restrict__ rowptr, const int* __restrict__ boff,
    const unsigned int* __restrict__ pairs,
    const float* __restrict__ y_in, const float* __restrict__ Ac,
    const float* __restrict__ Bc, float* __restrict__ y_out)
{
    int t = blockIdx.x * 256 + threadIdx.x;
    int node = t >> 2, l = t & 3;
    if (node >= N_NODES) return;
    int beg = rowptr[node] + boff[node >> 8];        // even -> 8B aligned
    int np1 = node + 1;
    int end = rowptr[np1] + (np1 < N_NODES ? boff[np1 >> 8] : 0);
    float sum = 0.0f;
    for (int j = beg + 2 * l; j < end; j += 8) {
        uint2 pp = *(const uint2*)(pairs + j);
        sum += (float)(pp.x & 0x7FFFu) * y_in[pp.x >> 15];
        sum += (float)(pp.y & 0x7FFFu) * y_in[pp.y >> 15];
    }
    sum += __shfl_xor(sum, 1, 64);
    sum += __shfl_xor(sum, 2, 64);
    if (l == 0) {
        y_out[node] = fmaf(Ac[node], sum * (1.0f/32767.0f) + y_in[node], Bc[node]);
    }
}

// ---------------------------------------------------------------------------
// LAST APPNP step: f_i = (1-a)*dis_i*(sum/32767 + y_i) + a*relu(mask_i).
// Writes ONLY f.
// ---------------------------------------------------------------------------
__global__ __launch_bounds__(256) void k_spmv_last(
    const int* __restrict__ rowptr, const int* __restrict__ boff,
    const unsigned int* __restrict__ pairs,
    const float* __restrict__ y_in, const float* __restrict__ dis,
    const float* __restrict__ mask, const float* __restrict__ alpha_p,
    float* __restrict__ f_out)
{
    int t = blockIdx.x * 256 + threadIdx.x;
    int node = t >> 2, l = t & 3;
    if (node >= N_NODES) return;
    int beg = rowptr[node] + boff[node >> 8];
    int np1 = node + 1;
    int end = rowptr[np1] + (np1 < N_NODES ? boff[np1 >> 8] : 0);
    float sum = 0.0f;
    for (int j = beg + 2 * l; j < end; j += 8) {
        uint2 pp = *(const uint2*)(pairs + j);
        sum += (float)(pp.x & 0x7FFFu) * y_in[pp.x >> 15];
        sum += (float)(pp.y & 0x7FFFu) * y_in[pp.y >> 15];
    }
    sum += __shfl_xor(sum, 1, 64);
    sum += __shfl_xor(sum, 2, 64);
    if (l == 0) {
        float di = dis[node];
        float alpha = alpha_p[0];
        float f0 = fmaxf(mask[node], 0.0f);
        f_out[node] = (1.0f - alpha) * di * (sum * (1.0f/32767.0f) + y_in[node]) + alpha * f0;
    }
}

extern "C" void kernel_launch(void* const* d_in, const int* in_sizes, int n_in,
                              void* d_out, int out_size, void* d_ws, size_t ws_size,
                              hipStream_t stream)
{
    const float* x     = (const float*)d_in[0];
    const float* mask  = (const float*)d_in[1];
    const int*   ei    = (const int*)  d_in[2];
    const float* W     = (const float*)d_in[3];
    const float* b     = (const float*)d_in[4];
    const float* alpha = (const float*)d_in[5];

    float* out_f = (float*)d_out;
    float* out_w = (float*)d_out + N_NODES;

    // workspace layout (float-element offsets)
    float* ws = (float*)d_ws;
    __half* hn    = (__half*)ws;                              // 6.4M halves (3.2M floats)
    unsigned int* pairs = (unsigned int*)(ws + 3200000);      // <=1.3M x 4B packed (padded)
    unsigned char* rank = (unsigned char*)(ws + 4550000);     // 1.25M x 1B
    unsigned long long* cnt64 = (unsigned long long*)(ws + 4870000);  // 100k x 8B
    int*   rowptr = (int*)  (ws + 5070000);                   // 100001 (alloc 100016)
    float* dis    =          ws + 5170016;                    // 100k
    float* y_a    =          ws + 5270016;                    // 100k
    float* y_b    =          ws + 5370016;                    // 100k
    float* Acoef  =          ws + 5470016;                    // 100k
    float* Bcoef  =          ws + 5570016;                    // 100k
    int*   bsum   = (int*)  (ws + 5670016);                   // 391 (alloc 512)
    int*   boff   = (int*)  (ws + 5670528);                   // 391

    const int segBlocks = (int)(((long long)N_NODES * 4 + 255) / 256);   // 1563

    // K0: zero(cnt64) + gemm_norm fused
    k_gemm_zero<<<ZERO_BLOCKS + GEMM_BLOCKS, 256, 0, stream>>>(x, W, b, hn, cnt64);
    // K1: cosine + packed rank/deg atomic (writes out_w, rank, cnt64)
    k_cos_rank<<<COSR_BLOCKS, 256, 0, stream>>>(ei, hn, cnt64, rank, out_w);
    // K2: even-padded rowptr scan + fused dis/y0/A/B
    k_scan1<<<NODE_BLOCKS, 256, 0, stream>>>(cnt64, rowptr, bsum, mask, alpha,
                                             dis, y_a, Acoef, Bcoef);
    // K3: block-offset scan
    k_scan2<<<1, 512, 0, stream>>>(bsum, boff, NODE_BLOCKS, rowptr);
    // K4: packed CSR placement (w>0 only) + pad-slot zeroing (fused node blocks)
    k_place<<<EDGE_BLOCKS + NODE_BLOCKS, 256, 0, stream>>>(
        ei, rank, rowptr, boff, out_w, cnt64, pairs);

    // K5..K8: 4 fast APPNP steps; K9: final step writing f
    k_spmv_fast<<<segBlocks, 256, 0, stream>>>(rowptr, boff, pairs, y_a, Acoef, Bcoef, y_b);
    k_spmv_fast<<<segBlocks, 256, 0, stream>>>(rowptr, boff, pairs, y_b, Acoef, Bcoef, y_a);
    k_spmv_fast<<<segBlocks, 256, 0, stream>>>(rowptr, boff, pairs, y_a, Acoef, Bcoef, y_b);
    k_spmv_fast<<<segBlocks, 256, 0, stream>>>(rowptr, boff, pairs, y_b, Acoef, Bcoef, y_a);
    k_spmv_last<<<segBlocks, 256, 0, stream>>>(rowptr, boff, pairs, y_a, dis, mask, alpha, out_f);
}